// Round 3
// baseline (184.377 us; speedup 1.0000x reference)
//
#include <hip/hip_runtime.h>
#include <math.h>

// Channel-wise min/max over a [C, N] fp32 tensor.
// Output layout: out[0..C) = min, out[C..2C) = max (tuple concat order).
//
// Perf notes (R3): rocprof showed the timed iteration is {512MB ws-poison
// fill (~77us) + kernel (~106us @ 1.26 TB/s)}. The one-1024-thread-block-
// per-row structure was stuck at ~1.26 TB/s across two ILP-very-different
// versions -> structural. This version uses the canonical streaming shape
// (8192 blocks x 256 threads, the same config class as the 87%-of-peak
// fillBuffer): each block reduces a 16KB row segment, partials go to d_ws,
// and a tiny deterministic finalize kernel folds 8 partials/row.
// (R4/R5: resubmitted unchanged — benches died on GPUAcquisitionTimeout,
// no counters were produced.)

#define BS2 256   // threads per block, stage 1 + finalize
#define BS 1024   // legacy fallback block size

// ---------------- Stage 1: per-(row,segment) partial min/max ----------------
template <int PER>
__global__ __launch_bounds__(BS2) void cw_minmax_part(
    const float* __restrict__ in, float* __restrict__ part,
    int nvec, int segs) {
    const int c   = blockIdx.x / segs;   // row
    const int seg = blockIdx.x % segs;   // segment within row
    const float4* __restrict__ p =
        reinterpret_cast<const float4*>(in) + (size_t)c * nvec
        + (size_t)seg * (BS2 * PER);

    // Batch PER independent global_load_dwordx4 before reducing.
    float4 v[PER];
    #pragma unroll
    for (int k = 0; k < PER; ++k)
        v[k] = p[threadIdx.x + k * BS2];

    float vmin = INFINITY, vmax = -INFINITY;
    #pragma unroll
    for (int k = 0; k < PER; ++k) {
        vmin = fminf(vmin, fminf(fminf(v[k].x, v[k].y), fminf(v[k].z, v[k].w)));
        vmax = fmaxf(vmax, fmaxf(fmaxf(v[k].x, v[k].y), fmaxf(v[k].z, v[k].w)));
    }

    // Wave-64 butterfly (xor: every lane ends with the result).
    #pragma unroll
    for (int off = 32; off > 0; off >>= 1) {
        vmin = fminf(vmin, __shfl_xor(vmin, off, 64));
        vmax = fmaxf(vmax, __shfl_xor(vmax, off, 64));
    }

    __shared__ float smin[BS2 / 64];
    __shared__ float smax[BS2 / 64];
    const int wave = threadIdx.x >> 6;
    const int lane = threadIdx.x & 63;
    if (lane == 0) { smin[wave] = vmin; smax[wave] = vmax; }
    __syncthreads();

    if (threadIdx.x == 0) {
        float m = smin[0], M = smax[0];
        #pragma unroll
        for (int w = 1; w < BS2 / 64; ++w) {
            m = fminf(m, smin[w]);
            M = fmaxf(M, smax[w]);
        }
        const int ntot = gridDim.x;          // = C * segs
        part[blockIdx.x] = m;                // mins: part[0 .. ntot)
        part[ntot + blockIdx.x] = M;         // maxs: part[ntot .. 2*ntot)
    }
}

// ---------------- Stage 2: fold `segs` partials per row (deterministic) -----
__global__ __launch_bounds__(BS2) void cw_minmax_fin(
    const float* __restrict__ part, float* __restrict__ out, int C, int segs) {
    const int t = blockIdx.x * BS2 + threadIdx.x;
    if (t >= 2 * C) return;
    const bool isMax = (t >= C);
    const int row = isMax ? t - C : t;
    const float* __restrict__ p =
        part + (isMax ? (size_t)C * segs : (size_t)0) + (size_t)row * segs;
    float r = p[0];
    if (isMax) {
        for (int s = 1; s < segs; ++s) r = fmaxf(r, p[s]);
    } else {
        for (int s = 1; s < segs; ++s) r = fminf(r, p[s]);
    }
    out[t] = r;   // t<C -> min_vals[row]; t>=C -> max_vals[row] at out[C+row]
}

// ---------------- Legacy fallback: one block per row ------------------------
template <int PER>
__global__ __launch_bounds__(BS) void cw_minmax_spec(
    const float* __restrict__ in, float* __restrict__ out, int nvec, int C) {
    const int c = blockIdx.x;
    const float4* __restrict__ row =
        reinterpret_cast<const float4*>(in) + (size_t)c * nvec;

    float4 v[PER];
    #pragma unroll
    for (int k = 0; k < PER; ++k)
        v[k] = row[threadIdx.x + k * BS];

    float vmin = INFINITY, vmax = -INFINITY;
    #pragma unroll
    for (int k = 0; k < PER; ++k) {
        vmin = fminf(vmin, fminf(fminf(v[k].x, v[k].y), fminf(v[k].z, v[k].w)));
        vmax = fmaxf(vmax, fmaxf(fmaxf(v[k].x, v[k].y), fmaxf(v[k].z, v[k].w)));
    }
    #pragma unroll
    for (int off = 32; off > 0; off >>= 1) {
        vmin = fminf(vmin, __shfl_xor(vmin, off, 64));
        vmax = fmaxf(vmax, __shfl_xor(vmax, off, 64));
    }
    __shared__ float smin[BS / 64];
    __shared__ float smax[BS / 64];
    const int wave = threadIdx.x >> 6;
    const int lane = threadIdx.x & 63;
    if (lane == 0) { smin[wave] = vmin; smax[wave] = vmax; }
    __syncthreads();
    if (threadIdx.x == 0) {
        float m = smin[0], M = smax[0];
        #pragma unroll
        for (int w = 1; w < BS / 64; ++w) {
            m = fminf(m, smin[w]);
            M = fmaxf(M, smax[w]);
        }
        out[c] = m;
        out[C + c] = M;
    }
}

// Generic fallback for shapes that don't divide evenly.
__global__ __launch_bounds__(256) void cw_minmax_generic(
    const float* __restrict__ in, float* __restrict__ out, int N, int C) {
    const int c = blockIdx.x;
    const float* __restrict__ row = in + (size_t)c * N;

    float vmin = INFINITY, vmax = -INFINITY;
    for (int i = threadIdx.x; i < N; i += blockDim.x) {
        float x = row[i];
        vmin = fminf(vmin, x);
        vmax = fmaxf(vmax, x);
    }
    #pragma unroll
    for (int off = 32; off > 0; off >>= 1) {
        vmin = fminf(vmin, __shfl_xor(vmin, off, 64));
        vmax = fmaxf(vmax, __shfl_xor(vmax, off, 64));
    }
    __shared__ float smin[4];
    __shared__ float smax[4];
    const int wave = threadIdx.x >> 6;
    const int lane = threadIdx.x & 63;
    if (lane == 0) { smin[wave] = vmin; smax[wave] = vmax; }
    __syncthreads();
    if (threadIdx.x == 0) {
        float m = smin[0], M = smax[0];
        for (int w = 1; w < 4; ++w) {
            m = fminf(m, smin[w]);
            M = fmaxf(M, smax[w]);
        }
        out[c] = m;
        out[C + c] = M;
    }
}

extern "C" void kernel_launch(void* const* d_in, const int* in_sizes, int n_in,
                              void* d_out, int out_size, void* d_ws, size_t ws_size,
                              hipStream_t stream) {
    const float* in = (const float*)d_in[0];
    float* out = (float*)d_out;

    const int C = out_size / 2;     // 1024
    const int N = in_sizes[0] / C;  // 32768

    if (N % 4 == 0) {
        const int nvec = N / 4;                 // float4 per row
        constexpr int PER = 4;                  // float4 per thread, stage 1
        if (nvec % (BS2 * PER) == 0) {
            const int segs = nvec / (BS2 * PER);           // 8 for N=32768
            const size_t need = (size_t)2 * C * segs * sizeof(float);  // 64 KB
            if (d_ws != nullptr && ws_size >= need && segs >= 1) {
                float* part = (float*)d_ws;
                cw_minmax_part<PER><<<C * segs, BS2, 0, stream>>>(in, part, nvec, segs);
                const int fin_blocks = (2 * C + BS2 - 1) / BS2;
                cw_minmax_fin<<<fin_blocks, BS2, 0, stream>>>(part, out, C, segs);
                return;
            }
        }
        // Legacy one-block-per-row path if ws unavailable / shape mismatch.
        if (nvec % BS == 0) {
            const int per = nvec / BS;
            switch (per) {
                case 4:  cw_minmax_spec<4><<<C, BS, 0, stream>>>(in, out, nvec, C);  return;
                case 8:  cw_minmax_spec<8><<<C, BS, 0, stream>>>(in, out, nvec, C);  return;
                case 16: cw_minmax_spec<16><<<C, BS, 0, stream>>>(in, out, nvec, C); return;
                default: break;
            }
        }
    }
    cw_minmax_generic<<<C, 256, 0, stream>>>(in, out, N, C);
}